// Round 17
// baseline (269.913 us; speedup 1.0000x reference)
//
#include <hip/hip_runtime.h>

#define NN   50000
#define NE   800000
#define HID  128
#define OUTD 40
#define NBLK 196  // ceil(NN/256)
#define LIN_BLKS ((NN + 127) / 128)   // 391
#define DEG_BLKS ((NE + 255) / 256)   // 3125
#define NREP 8

typedef float f32x4  __attribute__((ext_vector_type(4)));
typedef float f32x2  __attribute__((ext_vector_type(2)));
typedef int   i32x4  __attribute__((ext_vector_type(4)));
typedef short bf16x8 __attribute__((ext_vector_type(8)));

// ---------- helpers ----------
__device__ __forceinline__ f32x4 mfma(bf16x8 a, bf16x8 b, f32x4 c) {
  return __builtin_amdgcn_mfma_f32_16x16x32_bf16(a, b, c, 0, 0, 0);
}
__device__ __forceinline__ unsigned short f2bf(float f) {
  unsigned u = __builtin_bit_cast(unsigned, f);
  u += 0x7fffu + ((u >> 16) & 1u);
  return (unsigned short)(u >> 16);
}
__device__ __forceinline__ unsigned pack2(float lo, float hi) {
  return (unsigned)f2bf(lo) | ((unsigned)f2bf(hi) << 16);
}
__device__ __forceinline__ float bflo(unsigned v){ return __builtin_bit_cast(float, v << 16); }
__device__ __forceinline__ float bfhi(unsigned v){ return __builtin_bit_cast(float, v & 0xffff0000u); }
// HW fp8 e4m3 (OCP on gfx950) pack/unpack
__device__ __forceinline__ unsigned char f2fp8(float f) {
  int p = __builtin_amdgcn_cvt_pk_fp8_f32(f, f, 0, false);
  return (unsigned char)(p & 0xff);
}
// accumulate 16 fp8 values (one uint4) into a[16] via v_cvt_pk_f32_fp8
__device__ __forceinline__ void accfp8(float* a, uint4 v) {
  unsigned u[4] = {v.x, v.y, v.z, v.w};
#pragma unroll
  for (int i = 0; i < 4; i++) {
    f32x2 lo = __builtin_amdgcn_cvt_pk_f32_fp8((int)u[i], false);
    f32x2 hi = __builtin_amdgcn_cvt_pk_f32_fp8((int)u[i], true);
    a[i * 4 + 0] += lo[0]; a[i * 4 + 1] += lo[1];
    a[i * 4 + 2] += hi[0]; a[i * 4 + 3] += hi[1];
  }
}

// blocksum over the 8 replicated degree arrays
__global__ void k_blocksum(const int* __restrict__ deg8, int* __restrict__ bsum) {
  __shared__ int s[256];
  int t = threadIdx.x, i = blockIdx.x * 256 + t;
  int d = 0;
  if (i < NN) {
#pragma unroll
    for (int r = 0; r < NREP; r++) d += deg8[r * NN + i];
  }
  s[t] = d;
  __syncthreads();
  for (int o = 128; o > 0; o >>= 1) { if (t < o) s[t] += s[t + o]; __syncthreads(); }
  if (t == 0) bsum[blockIdx.x] = s[0];
}

// fused: per-block exclusive base + local scan; emits per-replica bases
__global__ void k_scan3(const int* __restrict__ deg8, const int* __restrict__ bsum,
                        int* __restrict__ offs, float* __restrict__ dinv,
                        int* __restrict__ abs8) {
  __shared__ int sb[256];
  __shared__ int s[256];
  int t = threadIdx.x, i = blockIdx.x * 256 + t;
  sb[t] = (t < NBLK && t < blockIdx.x) ? bsum[t] : 0;
  int dr[NREP];
  int v = 0;
  if (i < NN) {
#pragma unroll
    for (int r = 0; r < NREP; r++) { dr[r] = deg8[r * NN + i]; v += dr[r]; }
  }
  s[t] = v;
  __syncthreads();
  for (int o = 128; o > 0; o >>= 1) { if (t < o) sb[t] += sb[t + o]; __syncthreads(); }
  for (int o = 1; o < 256; o <<= 1) {
    int x = (t >= o) ? s[t - o] : 0;
    __syncthreads(); s[t] += x; __syncthreads();
  }
  int off = sb[0] + s[t] - v;  // exclusive within-array offset
  if (i < NN) {
    offs[i] = off;
    dinv[i] = 1.0f / (float)(v > 0 ? v : 1);
    int running = off;
#pragma unroll
    for (int r = 0; r < NREP; r++) { abs8[r * NN + i] = running; running += dr[r]; }
  }
  if (i == 0) offs[NN] = NE;
}

// no atomics: replica base + within-replica rank
__global__ void k_fill(const int* __restrict__ src, const int* __restrict__ dst,
                       const int* __restrict__ pos, const int* __restrict__ abs8,
                       int* __restrict__ csr) {
  int i = blockIdx.x * blockDim.x + threadIdx.x;
  if (i < NE) {
    int r = i & (NREP - 1);
    csr[abs8[r * NN + dst[i]] + pos[i]] = src[i];
  }
}

// ---------- weight prep: transpose + bf16 cast into ws; also zeros deg8 -------
__global__ void k_prep(const float* __restrict__ Win, const float* __restrict__ Wl,
                       const float* __restrict__ Wr, const float* __restrict__ Wc1,
                       const float* __restrict__ Wc2, unsigned short* __restrict__ wt,
                       int* __restrict__ deg8) {
  int idx = blockIdx.x * 256 + threadIdx.x;
  const int NT = ((8 * 16384 + 48 * 128 + 255) / 256) * 256;
  for (int j = idx; j < NREP * NN; j += NT) deg8[j] = 0;  // folded memset (8 copies)
  const int NMAIN = 8 * 16384;
  if (idx >= NMAIN + 48 * 128) return;
  float v;
  if (idx < NMAIN) {
    int m = idx >> 14, rem = idx & 16383;
    int n = rem >> 7, k = rem & 127;
    const float* s;
    if (m == 0) s = Win;
    else if (m <= 3) s = Wl + (m - 1) * 16384;
    else if (m <= 6) s = Wr + (m - 4) * 16384;
    else s = Wc1;
    v = s[k * 128 + n];
  } else {
    int rem = idx - NMAIN;
    int n = rem >> 7, k = rem & 127;
    v = (n < OUTD) ? Wc2[k * OUTD + n] : 0.f;
  }
  wt[idx] = f2bf(v);
}

// ---------- lin_in body (writes bf16 h + fp8 shadow via HW cvt) ----------
__device__ __forceinline__ void lin_in_body(int bid, const float* __restrict__ x,
                                            const unsigned short* __restrict__ Wt,
                                            const float* __restrict__ bias,
                                            unsigned short* __restrict__ hout,
                                            unsigned char* __restrict__ h8out) {
  const int lane = threadIdx.x & 63, w = threadIdx.x >> 6;
  const int wr = w >> 1, wc = w & 1;
  const int r15 = lane & 15, khi = lane >> 4;
  const int mbase = bid * 128 + wr * 64, nbase = wc * 64;
  f32x4 acc[4][4] = {};
#pragma unroll
  for (int ks = 0; ks < 4; ++ks) {
    const int kk = ks * 32 + khi * 8;
    bf16x8 af[4], bq[4];
#pragma unroll
    for (int i = 0; i < 4; i++) {
      int row = mbase + i * 16 + r15; row = row < NN ? row : NN - 1;
      const f32x4* p = (const f32x4*)(x + row * HID + kk);
      f32x4 lo = p[0], hi = p[1];
      i32x4 t;
      t[0] = pack2(lo[0], lo[1]); t[1] = pack2(lo[2], lo[3]);
      t[2] = pack2(hi[0], hi[1]); t[3] = pack2(hi[2], hi[3]);
      af[i] = __builtin_bit_cast(bf16x8, t);
    }
#pragma unroll
    for (int j = 0; j < 4; j++) {
      int col = nbase + j * 16 + r15;
      bq[j] = *(const bf16x8*)(Wt + col * HID + kk);
    }
#pragma unroll
    for (int i = 0; i < 4; i++)
#pragma unroll
      for (int j = 0; j < 4; j++) acc[i][j] = mfma(af[i], bq[j], acc[i][j]);
  }
  float b4[4];
#pragma unroll
  for (int j = 0; j < 4; j++) b4[j] = bias[nbase + j * 16 + r15];
#pragma unroll
  for (int i = 0; i < 4; i++) {
    const int rb = mbase + i * 16 + khi * 4;
#pragma unroll
    for (int e = 0; e < 4; e++) {
      const int r = rb + e;
      if (r < NN) {
#pragma unroll
        for (int j = 0; j < 4; j++) {
          float v = acc[i][j][e] + b4[j];
          const int col = nbase + j * 16 + r15;
          hout[r * HID + col] = f2bf(v);
          h8out[r * HID + col] = f2fp8(v);
        }
      }
    }
  }
}

// ---------- fused: h0 GEMM (blocks 0..390) || deg count+rank (blocks 391..) --
__global__ __launch_bounds__(256) void k_deg_lin(const int* __restrict__ dst,
                                                 int* __restrict__ deg8,
                                                 int* __restrict__ pos,
                                                 const float* __restrict__ x,
                                                 const unsigned short* __restrict__ Wt,
                                                 const float* __restrict__ bias,
                                                 unsigned short* __restrict__ hout,
                                                 unsigned char* __restrict__ h8out) {
  if (blockIdx.x < LIN_BLKS) {
    lin_in_body(blockIdx.x, x, Wt, bias, hout, h8out);
  } else {
    int i = (blockIdx.x - LIN_BLKS) * 256 + threadIdx.x;
    if (i < NE) {
      int r = i & (NREP - 1);
      pos[i] = atomicAdd(&deg8[r * NN + dst[i]], 1);
    }
  }
}

// ---------- aggregation: fp8 gather, eighth-wave uint4, HW cvt unpack ----------
// Row = 128B fp8 = ONE cacheline (halves line requests vs bf16). 8 lanes x
// 16B = one row; one 1KB instruction covers 8 rows; 16 rows/iter in flight.
__global__ __launch_bounds__(256) void k_agg(const unsigned char* __restrict__ h8,
                                             const int* __restrict__ csr,
                                             const int* __restrict__ offs,
                                             const float* __restrict__ dinv,
                                             unsigned short* __restrict__ agg) {
  const int lane = threadIdx.x & 63;
  const int c8 = lane & 7;   // uint4 index within 128B row
  const int o8 = lane >> 3;  // row within 8-row group, 0..7
  int gw = (blockIdx.x * 256 + (int)threadIdx.x) >> 6;
  const int nw = (gridDim.x * 256) >> 6;
  const uint4* h4 = (const uint4*)h8;  // row stride = 8 uint4
  uint4* ag4 = (uint4*)agg;            // bf16 row stride = 16 uint4
  for (int n = gw; n < NN; n += nw) {
    const int s = offs[n], e = offs[n + 1];
    float a[16];
#pragma unroll
    for (int j = 0; j < 16; j++) a[j] = 0.f;
    int k = s;
    int ia = 0, ib = 0;
    bool have = (k + 16 <= e);
    if (have) { ia = csr[k + o8]; ib = csr[k + 8 + o8]; }
    while (have) {
      uint4 va = h4[ia * 8 + c8];
      uint4 vb = h4[ib * 8 + c8];
      k += 16;
      have = (k + 16 <= e);
      if (have) { ia = csr[k + o8]; ib = csr[k + 8 + o8]; }  // prefetch
      accfp8(a, va);
      accfp8(a, vb);
    }
    for (; k < e; k += 8) {  // tail 1-15 rows, predicated per octant
      if (k + o8 < e) {
        uint4 v = h4[csr[k + o8] * 8 + c8];
        accfp8(a, v);
      }
    }
#pragma unroll
    for (int j = 0; j < 16; j++) {
      a[j] += __shfl_xor(a[j], 8);
      a[j] += __shfl_xor(a[j], 16);
      a[j] += __shfl_xor(a[j], 32);
    }
    if (o8 == 0) {  // lanes 0..7 write 32B of bf16 each
      float di = dinv[n];
      uint4 o0, o1;
      o0.x = pack2(a[0] * di, a[1] * di);
      o0.y = pack2(a[2] * di, a[3] * di);
      o0.z = pack2(a[4] * di, a[5] * di);
      o0.w = pack2(a[6] * di, a[7] * di);
      o1.x = pack2(a[8] * di, a[9] * di);
      o1.y = pack2(a[10] * di, a[11] * di);
      o1.z = pack2(a[12] * di, a[13] * di);
      o1.w = pack2(a[14] * di, a[15] * di);
      ag4[n * 16 + c8 * 2 + 0] = o0;
      ag4[n * 16 + c8 * 2 + 1] = o1;
    }
  }
}

// ---------- GEMM: h_new = relu(h @ Wl + agg @ Wr + bl) (+ fp8 shadow) --------
__global__ __launch_bounds__(256) void k_layer(const unsigned short* __restrict__ hp,
                                               const unsigned short* __restrict__ ag,
                                               const unsigned short* __restrict__ WtL,
                                               const unsigned short* __restrict__ WtR,
                                               const float* __restrict__ bias,
                                               unsigned short* __restrict__ hout,
                                               unsigned char* __restrict__ h8out) {
  const int lane = threadIdx.x & 63, w = threadIdx.x >> 6;
  const int wr = w >> 1, wc = w & 1;
  const int r15 = lane & 15, khi = lane >> 4;
  const int mbase = blockIdx.x * 128 + wr * 64, nbase = wc * 64;
  f32x4 acc[4][4] = {};
#pragma unroll
  for (int ph = 0; ph < 2; ++ph) {
    const unsigned short* A = ph ? ag : hp;
    const unsigned short* B = ph ? WtR : WtL;
#pragma unroll
    for (int ks = 0; ks < 4; ++ks) {
      const int kk = ks * 32 + khi * 8;
      bf16x8 af[4], bq[4];
#pragma unroll
      for (int i = 0; i < 4; i++) {
        int row = mbase + i * 16 + r15; row = row < NN ? row : NN - 1;
        af[i] = *(const bf16x8*)(A + row * HID + kk);
      }
#pragma unroll
      for (int j = 0; j < 4; j++) {
        int col = nbase + j * 16 + r15;
        bq[j] = *(const bf16x8*)(B + col * HID + kk);
      }
#pragma unroll
      for (int i = 0; i < 4; i++)
#pragma unroll
        for (int j = 0; j < 4; j++) acc[i][j] = mfma(af[i], bq[j], acc[i][j]);
    }
  }
  float b4[4];
#pragma unroll
  for (int j = 0; j < 4; j++) b4[j] = bias[nbase + j * 16 + r15];
#pragma unroll
  for (int i = 0; i < 4; i++) {
    const int rb = mbase + i * 16 + khi * 4;
#pragma unroll
    for (int e = 0; e < 4; e++) {
      const int r = rb + e;
      if (r < NN) {
#pragma unroll
        for (int j = 0; j < 4; j++) {
          float v = acc[i][j][e] + b4[j];
          v = fmaxf(v, 0.f);
          const int col = nbase + j * 16 + r15;
          hout[r * HID + col] = f2bf(v);
          h8out[r * HID + col] = f2fp8(v);
        }
      }
    }
  }
}

// ---------- classifier: out = relu((h1+h2+h3)@Wc1+bc1)@Wc2+bc2 ----------
__global__ __launch_bounds__(256) void k_cls(const unsigned short* __restrict__ h1,
                                             const unsigned short* __restrict__ h2,
                                             const unsigned short* __restrict__ h3,
                                             const unsigned short* __restrict__ WtC1,
                                             const float* __restrict__ bc1,
                                             const unsigned short* __restrict__ WtC2,
                                             const float* __restrict__ bc2,
                                             float* __restrict__ out) {
  __shared__ unsigned short hc[128 * 136];  // padded row stride 136
  const int lane = threadIdx.x & 63, w = threadIdx.x >> 6;
  const int wr = w >> 1, wc = w & 1;
  const int r15 = lane & 15, khi = lane >> 4;
  const int mbase = blockIdx.x * 128 + wr * 64, nbase = wc * 64;
  // stage 1: hc = relu((h1+h2+h3) @ Wc1 + bc1)
  {
    f32x4 acc[4][4] = {};
#pragma unroll
    for (int ks = 0; ks < 4; ++ks) {
      const int kk = ks * 32 + khi * 8;
      bf16x8 af[4], bq[4];
#pragma unroll
      for (int i = 0; i < 4; i++) {
        int row = mbase + i * 16 + r15; row = row < NN ? row : NN - 1;
        i32x4 u = *(const i32x4*)(h1 + row * HID + kk);
        i32x4 v = *(const i32x4*)(h2 + row * HID + kk);
        i32x4 q = *(const i32x4*)(h3 + row * HID + kk);
        i32x4 t;
#pragma unroll
        for (int cc = 0; cc < 4; cc++) {
          unsigned uu = u[cc], vv = v[cc], qq = q[cc];
          t[cc] = pack2(bflo(uu) + bflo(vv) + bflo(qq), bfhi(uu) + bfhi(vv) + bfhi(qq));
        }
        af[i] = __builtin_bit_cast(bf16x8, t);
      }
#pragma unroll
      for (int j = 0; j < 4; j++) {
        int col = nbase + j * 16 + r15;
        bq[j] = *(const bf16x8*)(WtC1 + col * HID + kk);
      }
#pragma unroll
      for (int i = 0; i < 4; i++)
#pragma unroll
        for (int j = 0; j < 4; j++) acc[i][j] = mfma(af[i], bq[j], acc[i][j]);
    }
    float b4[4];
#pragma unroll
    for (int j = 0; j < 4; j++) b4[j] = bc1[nbase + j * 16 + r15];
#pragma unroll
    for (int i = 0; i < 4; i++) {
      const int rT = wr * 64 + i * 16 + khi * 4;
#pragma unroll
      for (int e = 0; e < 4; e++) {
#pragma unroll
        for (int j = 0; j < 4; j++) {
          float v = fmaxf(acc[i][j][e] + b4[j], 0.f);
          hc[(rT + e) * 136 + nbase + j * 16 + r15] = f2bf(v);
        }
      }
    }
  }
  __syncthreads();
  // stage 2: out = hc @ Wc2 + bc2
  {
    f32x4 a2[2][3] = {};
#pragma unroll
    for (int ks = 0; ks < 4; ++ks) {
      const int kk = ks * 32 + khi * 8;
      bf16x8 af[2], bq[3];
#pragma unroll
      for (int i = 0; i < 2; i++) {
        int rT = w * 32 + i * 16 + r15;
        af[i] = *(const bf16x8*)&hc[rT * 136 + kk];
      }
#pragma unroll
      for (int j = 0; j < 3; j++) {
        int col = j * 16 + r15;
        bq[j] = *(const bf16x8*)(WtC2 + col * HID + kk);
      }
#pragma unroll
      for (int i = 0; i < 2; i++)
#pragma unroll
        for (int j = 0; j < 3; j++) a2[i][j] = mfma(af[i], bq[j], a2[i][j]);
    }
#pragma unroll
    for (int j = 0; j < 3; j++) {
      const int col = j * 16 + r15;
      const float b = (col < OUTD) ? bc2[col] : 0.f;
#pragma unroll
      for (int i = 0; i < 2; i++) {
        const int rT = w * 32 + i * 16 + khi * 4;
#pragma unroll
        for (int e = 0; e < 4; e++) {
          const int gr = blockIdx.x * 128 + rT + e;
          if (gr < NN && col < OUTD) out[gr * OUTD + col] = a2[i][j][e] + b;
        }
      }
    }
  }
}

// ---------- launch ----------
extern "C" void kernel_launch(void* const* d_in, const int* in_sizes, int n_in,
                              void* d_out, int out_size, void* d_ws, size_t ws_size,
                              hipStream_t stream) {
  (void)in_sizes; (void)n_in; (void)out_size; (void)ws_size;
  const float* x   = (const float*)d_in[0];
  const int*   ei  = (const int*)d_in[1];
  const float* Win = (const float*)d_in[2];
  const float* bin = (const float*)d_in[3];
  const float* Wl  = (const float*)d_in[4];
  const float* Wr  = (const float*)d_in[5];
  const float* bl  = (const float*)d_in[6];
  const float* Wc1 = (const float*)d_in[7];
  const float* bc1 = (const float*)d_in[8];
  const float* Wc2 = (const float*)d_in[9];
  const float* bc2 = (const float*)d_in[10];
  float* out = (float*)d_out;

  char* ws = (char*)d_ws;
  size_t off = 0;
  auto take = [&](size_t bytes) -> char* {
    char* p = ws + off; off = (off + bytes + 255) & ~(size_t)255; return p;
  };
  int* deg8       = (int*)take((size_t)NREP * NN * 4);
  int* abs8       = (int*)take((size_t)NREP * NN * 4);
  int* offs       = (int*)take((size_t)(NN + 1) * 4);
  int* pos        = (int*)take((size_t)NE * 4);
  int* bsum       = (int*)take(256 * 4);
  float* dinv     = (float*)take((size_t)NN * 4);
  int* csr        = (int*)take((size_t)NE * 4);
  unsigned short* wt  = (unsigned short*)take((size_t)(8 * 16384 + 48 * 128) * 2);
  unsigned short* h0  = (unsigned short*)take((size_t)NN * HID * 2);
  unsigned short* h1  = (unsigned short*)take((size_t)NN * HID * 2);
  unsigned short* h2  = (unsigned short*)take((size_t)NN * HID * 2);
  unsigned short* h3  = (unsigned short*)take((size_t)NN * HID * 2);
  unsigned short* agg = (unsigned short*)take((size_t)NN * HID * 2);
  unsigned char* h8_0 = (unsigned char*)take((size_t)NN * HID);
  unsigned char* h8_1 = (unsigned char*)take((size_t)NN * HID);
  unsigned char* h8_2 = (unsigned char*)take((size_t)NN * HID);

  const int* esrc = ei;
  const int* edst = ei + NE;

  k_prep<<<(8 * 16384 + 48 * 128 + 255) / 256, 256, 0, stream>>>(Win, Wl, Wr, Wc1, Wc2, wt, deg8);
  k_deg_lin<<<LIN_BLKS + DEG_BLKS, 256, 0, stream>>>(edst, deg8, pos, x, wt, bin, h0, h8_0);
  k_blocksum<<<NBLK, 256, 0, stream>>>(deg8, bsum);
  k_scan3<<<NBLK, 256, 0, stream>>>(deg8, bsum, offs, dinv, abs8);
  k_fill<<<(NE + 255) / 256, 256, 0, stream>>>(esrc, edst, pos, abs8, csr);

  unsigned short* hs[4] = {h0, h1, h2, h3};
  unsigned char* h8s[3] = {h8_0, h8_1, h8_2};
  for (int i = 0; i < 3; i++) {
    k_agg<<<2048, 256, 0, stream>>>(h8s[i], csr, offs, dinv, agg);
    unsigned char* h8next = (i < 2) ? h8s[i + 1] : h8_0;  // layer 2 shadow unused
    k_layer<<<(NN + 127) / 128, 256, 0, stream>>>(hs[i], agg, wt + (1 + i) * 16384,
                                                  wt + (4 + i) * 16384, bl + i * HID,
                                                  hs[i + 1], h8next);
  }
  k_cls<<<(NN + 127) / 128, 256, 0, stream>>>(h1, h2, h3, wt + 7 * 16384, bc1,
                                              wt + 8 * 16384, bc2, out);
}

// Round 18
// 234.498 us; speedup vs baseline: 1.1510x; 1.1510x over previous
//
#include <hip/hip_runtime.h>

#define NN   50000
#define NE   800000
#define HID  128
#define OUTD 40
#define NBLK 196  // ceil(NN/256)
#define LIN_BLKS ((NN + 127) / 128)   // 391
#define DEG_BLKS ((NE + 255) / 256)   // 3125
#define NREP 8

typedef float f32x4  __attribute__((ext_vector_type(4)));
typedef int   i32x4  __attribute__((ext_vector_type(4)));
typedef short bf16x8 __attribute__((ext_vector_type(8)));

// ---------- helpers ----------
__device__ __forceinline__ f32x4 mfma(bf16x8 a, bf16x8 b, f32x4 c) {
  return __builtin_amdgcn_mfma_f32_16x16x32_bf16(a, b, c, 0, 0, 0);
}
__device__ __forceinline__ unsigned short f2bf(float f) {
  unsigned u = __builtin_bit_cast(unsigned, f);
  u += 0x7fffu + ((u >> 16) & 1u);
  return (unsigned short)(u >> 16);
}
__device__ __forceinline__ unsigned pack2(float lo, float hi) {
  return (unsigned)f2bf(lo) | ((unsigned)f2bf(hi) << 16);
}
__device__ __forceinline__ float bflo(unsigned v){ return __builtin_bit_cast(float, v << 16); }
__device__ __forceinline__ float bfhi(unsigned v){ return __builtin_bit_cast(float, v & 0xffff0000u); }
__device__ __forceinline__ void acc8(float* a, uint4 v) {
  a[0] += bflo(v.x); a[1] += bfhi(v.x);
  a[2] += bflo(v.y); a[3] += bfhi(v.y);
  a[4] += bflo(v.z); a[5] += bfhi(v.z);
  a[6] += bflo(v.w); a[7] += bfhi(v.w);
}

// blocksum over the 8 replicated degree arrays
__global__ void k_blocksum(const int* __restrict__ deg8, int* __restrict__ bsum) {
  __shared__ int s[256];
  int t = threadIdx.x, i = blockIdx.x * 256 + t;
  int d = 0;
  if (i < NN) {
#pragma unroll
    for (int r = 0; r < NREP; r++) d += deg8[r * NN + i];
  }
  s[t] = d;
  __syncthreads();
  for (int o = 128; o > 0; o >>= 1) { if (t < o) s[t] += s[t + o]; __syncthreads(); }
  if (t == 0) bsum[blockIdx.x] = s[0];
}

// fused: per-block exclusive base + local scan; emits per-replica bases
__global__ void k_scan3(const int* __restrict__ deg8, const int* __restrict__ bsum,
                        int* __restrict__ offs, float* __restrict__ dinv,
                        int* __restrict__ abs8) {
  __shared__ int sb[256];
  __shared__ int s[256];
  int t = threadIdx.x, i = blockIdx.x * 256 + t;
  sb[t] = (t < NBLK && t < blockIdx.x) ? bsum[t] : 0;
  int dr[NREP];
  int v = 0;
  if (i < NN) {
#pragma unroll
    for (int r = 0; r < NREP; r++) { dr[r] = deg8[r * NN + i]; v += dr[r]; }
  }
  s[t] = v;
  __syncthreads();
  for (int o = 128; o > 0; o >>= 1) { if (t < o) sb[t] += sb[t + o]; __syncthreads(); }
  for (int o = 1; o < 256; o <<= 1) {
    int x = (t >= o) ? s[t - o] : 0;
    __syncthreads(); s[t] += x; __syncthreads();
  }
  int off = sb[0] + s[t] - v;  // exclusive within-array offset
  if (i < NN) {
    offs[i] = off;
    dinv[i] = 1.0f / (float)(v > 0 ? v : 1);
    int running = off;
#pragma unroll
    for (int r = 0; r < NREP; r++) { abs8[r * NN + i] = running; running += dr[r]; }
  }
  if (i == 0) offs[NN] = NE;
}

// no atomics: replica base + within-replica rank
__global__ void k_fill(const int* __restrict__ src, const int* __restrict__ dst,
                       const int* __restrict__ pos, const int* __restrict__ abs8,
                       int* __restrict__ csr) {
  int i = blockIdx.x * blockDim.x + threadIdx.x;
  if (i < NE) {
    int r = i & (NREP - 1);
    csr[abs8[r * NN + dst[i]] + pos[i]] = src[i];
  }
}

// ---------- weight prep: transpose + bf16 cast into ws; also zeros deg8 -------
__global__ void k_prep(const float* __restrict__ Win, const float* __restrict__ Wl,
                       const float* __restrict__ Wr, const float* __restrict__ Wc1,
                       const float* __restrict__ Wc2, unsigned short* __restrict__ wt,
                       int* __restrict__ deg8) {
  int idx = blockIdx.x * 256 + threadIdx.x;
  const int NT = ((8 * 16384 + 48 * 128 + 255) / 256) * 256;
  for (int j = idx; j < NREP * NN; j += NT) deg8[j] = 0;  // folded memset (8 copies)
  const int NMAIN = 8 * 16384;
  if (idx >= NMAIN + 48 * 128) return;
  float v;
  if (idx < NMAIN) {
    int m = idx >> 14, rem = idx & 16383;
    int n = rem >> 7, k = rem & 127;
    const float* s;
    if (m == 0) s = Win;
    else if (m <= 3) s = Wl + (m - 1) * 16384;
    else if (m <= 6) s = Wr + (m - 4) * 16384;
    else s = Wc1;
    v = s[k * 128 + n];
  } else {
    int rem = idx - NMAIN;
    int n = rem >> 7, k = rem & 127;
    v = (n < OUTD) ? Wc2[k * OUTD + n] : 0.f;
  }
  wt[idx] = f2bf(v);
}

// ---------- lin_in body (r10 k_lin_in, as device function) ----------
__device__ __forceinline__ void lin_in_body(int bid, const float* __restrict__ x,
                                            const unsigned short* __restrict__ Wt,
                                            const float* __restrict__ bias,
                                            unsigned short* __restrict__ hout) {
  const int lane = threadIdx.x & 63, w = threadIdx.x >> 6;
  const int wr = w >> 1, wc = w & 1;
  const int r15 = lane & 15, khi = lane >> 4;
  const int mbase = bid * 128 + wr * 64, nbase = wc * 64;
  f32x4 acc[4][4] = {};
#pragma unroll
  for (int ks = 0; ks < 4; ++ks) {
    const int kk = ks * 32 + khi * 8;
    bf16x8 af[4], bq[4];
#pragma unroll
    for (int i = 0; i < 4; i++) {
      int row = mbase + i * 16 + r15; row = row < NN ? row : NN - 1;
      const f32x4* p = (const f32x4*)(x + row * HID + kk);
      f32x4 lo = p[0], hi = p[1];
      i32x4 t;
      t[0] = pack2(lo[0], lo[1]); t[1] = pack2(lo[2], lo[3]);
      t[2] = pack2(hi[0], hi[1]); t[3] = pack2(hi[2], hi[3]);
      af[i] = __builtin_bit_cast(bf16x8, t);
    }
#pragma unroll
    for (int j = 0; j < 4; j++) {
      int col = nbase + j * 16 + r15;
      bq[j] = *(const bf16x8*)(Wt + col * HID + kk);
    }
#pragma unroll
    for (int i = 0; i < 4; i++)
#pragma unroll
      for (int j = 0; j < 4; j++) acc[i][j] = mfma(af[i], bq[j], acc[i][j]);
  }
  float b4[4];
#pragma unroll
  for (int j = 0; j < 4; j++) b4[j] = bias[nbase + j * 16 + r15];
#pragma unroll
  for (int i = 0; i < 4; i++) {
    const int rb = mbase + i * 16 + khi * 4;
#pragma unroll
    for (int e = 0; e < 4; e++) {
      const int r = rb + e;
      if (r < NN) {
#pragma unroll
        for (int j = 0; j < 4; j++)
          hout[r * HID + nbase + j * 16 + r15] = f2bf(acc[i][j][e] + b4[j]);
      }
    }
  }
}

// ---------- fused: h0 GEMM (blocks 0..390) || deg count+rank (blocks 391..) --
__global__ __launch_bounds__(256) void k_deg_lin(const int* __restrict__ dst,
                                                 int* __restrict__ deg8,
                                                 int* __restrict__ pos,
                                                 const float* __restrict__ x,
                                                 const unsigned short* __restrict__ Wt,
                                                 const float* __restrict__ bias,
                                                 unsigned short* __restrict__ hout) {
  if (blockIdx.x < LIN_BLKS) {
    lin_in_body(blockIdx.x, x, Wt, bias, hout);
  } else {
    int i = (blockIdx.x - LIN_BLKS) * 256 + threadIdx.x;
    if (i < NE) {
      int r = i & (NREP - 1);
      pos[i] = atomicAdd(&deg8[r * NN + dst[i]], 1);
    }
  }
}

// ---------- aggregation: quarter-wave uint4, 3-deep pipeline (12 rows/iter) --
// Only lever that has ever paid on this gather: more independent loads in
// flight within the VGPR budget. 3 banks x 8 acc + 3 uint4 loads ~ 55 VGPR,
// under the 64-VGPR occupancy cliff.
__global__ __launch_bounds__(256) void k_agg(const unsigned short* __restrict__ h,
                                             const int* __restrict__ csr,
                                             const int* __restrict__ offs,
                                             const float* __restrict__ dinv,
                                             unsigned short* __restrict__ agg) {
  const int lane = threadIdx.x & 63;
  const int c = lane & 15;   // uint4 index within row (16 x 16B = 256B)
  const int q = lane >> 4;   // quarter 0..3: row within 4-row group
  int gw = (blockIdx.x * 256 + (int)threadIdx.x) >> 6;
  const int nw = (gridDim.x * 256) >> 6;
  const uint4* h4 = (const uint4*)h;  // row stride = 16 uint4
  uint4* ag4 = (uint4*)agg;
  for (int n = gw; n < NN; n += nw) {
    const int s = offs[n], e = offs[n + 1];
    float a[8] = {0, 0, 0, 0, 0, 0, 0, 0};
    float b[8] = {0, 0, 0, 0, 0, 0, 0, 0};
    float d[8] = {0, 0, 0, 0, 0, 0, 0, 0};
    int k = s;
    int ia = 0, ib = 0, ic = 0;
    bool have = (k + 12 <= e);
    if (have) { ia = csr[k + q]; ib = csr[k + 4 + q]; ic = csr[k + 8 + q]; }
    while (have) {
      uint4 va = h4[ia * 16 + c];
      uint4 vb = h4[ib * 16 + c];
      uint4 vc = h4[ic * 16 + c];
      k += 12;
      have = (k + 12 <= e);
      if (have) { ia = csr[k + q]; ib = csr[k + 4 + q]; ic = csr[k + 8 + q]; }
      acc8(a, va);
      acc8(b, vb);
      acc8(d, vc);
    }
    // tail 0-11 rows: two independent predicated streams
    for (; k + 8 <= e; k += 8) {
      uint4 va = h4[csr[k + q] * 16 + c];
      uint4 vb = h4[csr[k + 4 + q] * 16 + c];
      acc8(a, va);
      acc8(b, vb);
    }
    for (; k < e; k += 4) {
      if (k + q < e) {
        uint4 v = h4[csr[k + q] * 16 + c];
        acc8(a, v);
      }
    }
    float f0 = a[0] + b[0] + d[0], f1 = a[1] + b[1] + d[1];
    float f2 = a[2] + b[2] + d[2], f3 = a[3] + b[3] + d[3];
    float f4 = a[4] + b[4] + d[4], f5 = a[5] + b[5] + d[5];
    float f6 = a[6] + b[6] + d[6], f7 = a[7] + b[7] + d[7];
    f0 += __shfl_xor(f0, 16); f1 += __shfl_xor(f1, 16);
    f2 += __shfl_xor(f2, 16); f3 += __shfl_xor(f3, 16);
    f4 += __shfl_xor(f4, 16); f5 += __shfl_xor(f5, 16);
    f6 += __shfl_xor(f6, 16); f7 += __shfl_xor(f7, 16);
    f0 += __shfl_xor(f0, 32); f1 += __shfl_xor(f1, 32);
    f2 += __shfl_xor(f2, 32); f3 += __shfl_xor(f3, 32);
    f4 += __shfl_xor(f4, 32); f5 += __shfl_xor(f5, 32);
    f6 += __shfl_xor(f6, 32); f7 += __shfl_xor(f7, 32);
    if (q == 0) {
      float di = dinv[n];
      uint4 o;
      o.x = pack2(f0 * di, f1 * di);
      o.y = pack2(f2 * di, f3 * di);
      o.z = pack2(f4 * di, f5 * di);
      o.w = pack2(f6 * di, f7 * di);
      ag4[n * 16 + c] = o;
    }
  }
}

// ---------- GEMM: h_new = relu(h @ Wl + agg @ Wr + bl) (bf16 in/out) ----------
__global__ __launch_bounds__(256) void k_layer(const unsigned short* __restrict__ hp,
                                               const unsigned short* __restrict__ ag,
                                               const unsigned short* __restrict__ WtL,
                                               const unsigned short* __restrict__ WtR,
                                               const float* __restrict__ bias,
                                               unsigned short* __restrict__ hout) {
  const int lane = threadIdx.x & 63, w = threadIdx.x >> 6;
  const int wr = w >> 1, wc = w & 1;
  const int r15 = lane & 15, khi = lane >> 4;
  const int mbase = blockIdx.x * 128 + wr * 64, nbase = wc * 64;
  f32x4 acc[4][4] = {};
#pragma unroll
  for (int ph = 0; ph < 2; ++ph) {
    const unsigned short* A = ph ? ag : hp;
    const unsigned short* B = ph ? WtR : WtL;
#pragma unroll
    for (int ks = 0; ks < 4; ++ks) {
      const int kk = ks * 32 + khi * 8;
      bf16x8 af[4], bq[4];
#pragma unroll
      for (int i = 0; i < 4; i++) {
        int row = mbase + i * 16 + r15; row = row < NN ? row : NN - 1;
        af[i] = *(const bf16x8*)(A + row * HID + kk);
      }
#pragma unroll
      for (int j = 0; j < 4; j++) {
        int col = nbase + j * 16 + r15;
        bq[j] = *(const bf16x8*)(B + col * HID + kk);
      }
#pragma unroll
      for (int i = 0; i < 4; i++)
#pragma unroll
        for (int j = 0; j < 4; j++) acc[i][j] = mfma(af[i], bq[j], acc[i][j]);
    }
  }
  float b4[4];
#pragma unroll
  for (int j = 0; j < 4; j++) b4[j] = bias[nbase + j * 16 + r15];
#pragma unroll
  for (int i = 0; i < 4; i++) {
    const int rb = mbase + i * 16 + khi * 4;
#pragma unroll
    for (int e = 0; e < 4; e++) {
      const int r = rb + e;
      if (r < NN) {
#pragma unroll
        for (int j = 0; j < 4; j++) {
          float v = acc[i][j][e] + b4[j];
          v = fmaxf(v, 0.f);
          hout[r * HID + nbase + j * 16 + r15] = f2bf(v);
        }
      }
    }
  }
}

// ---------- classifier: out = relu((h1+h2+h3)@Wc1+bc1)@Wc2+bc2 ----------
__global__ __launch_bounds__(256) void k_cls(const unsigned short* __restrict__ h1,
                                             const unsigned short* __restrict__ h2,
                                             const unsigned short* __restrict__ h3,
                                             const unsigned short* __restrict__ WtC1,
                                             const float* __restrict__ bc1,
                                             const unsigned short* __restrict__ WtC2,
                                             const float* __restrict__ bc2,
                                             float* __restrict__ out) {
  __shared__ unsigned short hc[128 * 136];  // padded row stride 136
  const int lane = threadIdx.x & 63, w = threadIdx.x >> 6;
  const int wr = w >> 1, wc = w & 1;
  const int r15 = lane & 15, khi = lane >> 4;
  const int mbase = blockIdx.x * 128 + wr * 64, nbase = wc * 64;
  // stage 1: hc = relu((h1+h2+h3) @ Wc1 + bc1)
  {
    f32x4 acc[4][4] = {};
#pragma unroll
    for (int ks = 0; ks < 4; ++ks) {
      const int kk = ks * 32 + khi * 8;
      bf16x8 af[4], bq[4];
#pragma unroll
      for (int i = 0; i < 4; i++) {
        int row = mbase + i * 16 + r15; row = row < NN ? row : NN - 1;
        i32x4 u = *(const i32x4*)(h1 + row * HID + kk);
        i32x4 v = *(const i32x4*)(h2 + row * HID + kk);
        i32x4 q = *(const i32x4*)(h3 + row * HID + kk);
        i32x4 t;
#pragma unroll
        for (int cc = 0; cc < 4; cc++) {
          unsigned uu = u[cc], vv = v[cc], qq = q[cc];
          t[cc] = pack2(bflo(uu) + bflo(vv) + bflo(qq), bfhi(uu) + bfhi(vv) + bfhi(qq));
        }
        af[i] = __builtin_bit_cast(bf16x8, t);
      }
#pragma unroll
      for (int j = 0; j < 4; j++) {
        int col = nbase + j * 16 + r15;
        bq[j] = *(const bf16x8*)(WtC1 + col * HID + kk);
      }
#pragma unroll
      for (int i = 0; i < 4; i++)
#pragma unroll
        for (int j = 0; j < 4; j++) acc[i][j] = mfma(af[i], bq[j], acc[i][j]);
    }
    float b4[4];
#pragma unroll
    for (int j = 0; j < 4; j++) b4[j] = bc1[nbase + j * 16 + r15];
#pragma unroll
    for (int i = 0; i < 4; i++) {
      const int rT = wr * 64 + i * 16 + khi * 4;
#pragma unroll
      for (int e = 0; e < 4; e++) {
#pragma unroll
        for (int j = 0; j < 4; j++) {
          float v = fmaxf(acc[i][j][e] + b4[j], 0.f);
          hc[(rT + e) * 136 + nbase + j * 16 + r15] = f2bf(v);
        }
      }
    }
  }
  __syncthreads();
  // stage 2: out = hc @ Wc2 + bc2
  {
    f32x4 a2[2][3] = {};
#pragma unroll
    for (int ks = 0; ks < 4; ++ks) {
      const int kk = ks * 32 + khi * 8;
      bf16x8 af[2], bq[3];
#pragma unroll
      for (int i = 0; i < 2; i++) {
        int rT = w * 32 + i * 16 + r15;
        af[i] = *(const bf16x8*)&hc[rT * 136 + kk];
      }
#pragma unroll
      for (int j = 0; j < 3; j++) {
        int col = j * 16 + r15;
        bq[j] = *(const bf16x8*)(WtC2 + col * HID + kk);
      }
#pragma unroll
      for (int i = 0; i < 2; i++)
#pragma unroll
        for (int j = 0; j < 3; j++) a2[i][j] = mfma(af[i], bq[j], a2[i][j]);
    }
#pragma unroll
    for (int j = 0; j < 3; j++) {
      const int col = j * 16 + r15;
      const float b = (col < OUTD) ? bc2[col] : 0.f;
#pragma unroll
      for (int i = 0; i < 2; i++) {
        const int rT = w * 32 + i * 16 + khi * 4;
#pragma unroll
        for (int e = 0; e < 4; e++) {
          const int gr = blockIdx.x * 128 + rT + e;
          if (gr < NN && col < OUTD) out[gr * OUTD + col] = a2[i][j][e] + b;
        }
      }
    }
  }
}

// ---------- launch ----------
extern "C" void kernel_launch(void* const* d_in, const int* in_sizes, int n_in,
                              void* d_out, int out_size, void* d_ws, size_t ws_size,
                              hipStream_t stream) {
  (void)in_sizes; (void)n_in; (void)out_size; (void)ws_size;
  const float* x   = (const float*)d_in[0];
  const int*   ei  = (const int*)d_in[1];
  const float* Win = (const float*)d_in[2];
  const float* bin = (const float*)d_in[3];
  const float* Wl  = (const float*)d_in[4];
  const float* Wr  = (const float*)d_in[5];
  const float* bl  = (const float*)d_in[6];
  const float* Wc1 = (const float*)d_in[7];
  const float* bc1 = (const float*)d_in[8];
  const float* Wc2 = (const float*)d_in[9];
  const float* bc2 = (const float*)d_in[10];
  float* out = (float*)d_out;

  char* ws = (char*)d_ws;
  size_t off = 0;
  auto take = [&](size_t bytes) -> char* {
    char* p = ws + off; off = (off + bytes + 255) & ~(size_t)255; return p;
  };
  int* deg8       = (int*)take((size_t)NREP * NN * 4);
  int* abs8       = (int*)take((size_t)NREP * NN * 4);
  int* offs       = (int*)take((size_t)(NN + 1) * 4);
  int* pos        = (int*)take((size_t)NE * 4);
  int* bsum       = (int*)take(256 * 4);
  float* dinv     = (float*)take((size_t)NN * 4);
  int* csr        = (int*)take((size_t)NE * 4);
  unsigned short* wt  = (unsigned short*)take((size_t)(8 * 16384 + 48 * 128) * 2);
  unsigned short* h0  = (unsigned short*)take((size_t)NN * HID * 2);
  unsigned short* h1  = (unsigned short*)take((size_t)NN * HID * 2);
  unsigned short* h2  = (unsigned short*)take((size_t)NN * HID * 2);
  unsigned short* h3  = (unsigned short*)take((size_t)NN * HID * 2);
  unsigned short* agg = (unsigned short*)take((size_t)NN * HID * 2);

  const int* esrc = ei;
  const int* edst = ei + NE;

  k_prep<<<(8 * 16384 + 48 * 128 + 255) / 256, 256, 0, stream>>>(Win, Wl, Wr, Wc1, Wc2, wt, deg8);
  k_deg_lin<<<LIN_BLKS + DEG_BLKS, 256, 0, stream>>>(edst, deg8, pos, x, wt, bin, h0);
  k_blocksum<<<NBLK, 256, 0, stream>>>(deg8, bsum);
  k_scan3<<<NBLK, 256, 0, stream>>>(deg8, bsum, offs, dinv, abs8);
  k_fill<<<(NE + 255) / 256, 256, 0, stream>>>(esrc, edst, pos, abs8, csr);

  unsigned short* hs[4] = {h0, h1, h2, h3};
  for (int i = 0; i < 3; i++) {
    k_agg<<<2048, 256, 0, stream>>>(hs[i], csr, offs, dinv, agg);
    k_layer<<<(NN + 127) / 128, 256, 0, stream>>>(hs[i], agg, wt + (1 + i) * 16384,
                                                  wt + (4 + i) * 16384, bl + i * HID, hs[i + 1]);
  }
  k_cls<<<(NN + 127) / 128, 256, 0, stream>>>(h1, h2, h3, wt + 7 * 16384, bc1,
                                              wt + 8 * 16384, bc2, out);
}